// Round 8
// baseline (414.138 us; speedup 1.0000x reference)
//
#include <hip/hip_runtime.h>
#include <cstdint>
#include <cstddef>

typedef _Float16 h8 __attribute__((ext_vector_type(8)));
typedef _Float16 h4 __attribute__((ext_vector_type(4)));
typedef __fp16 fp16x2 __attribute__((ext_vector_type(2)));
typedef float f4 __attribute__((ext_vector_type(4)));

#define MFMA(a, b, c) __builtin_amdgcn_mfma_f32_16x16x32_f16((a), (b), (c), 0, 0, 0)

__device__ __forceinline__ void gl_lds16(const void* g, void* l) {
  __builtin_amdgcn_global_load_lds((const __attribute__((address_space(1))) void*)g,
                                   (__attribute__((address_space(3))) void*)l, 16, 0, 0);
}

// swizzled LDS fragment read: row r, 16B chunk ch, 8 chunks per 64-f16 row
__device__ __forceinline__ h8 lds_frag(const char* base, int r, int ch) {
  return *(const h8*)(base + ((r * 8 + (ch ^ (r & 7))) * 16));
}

// barrier with compile-time memory fences on both sides (no LDS op may cross)
__device__ __forceinline__ void BAR() {
  asm volatile("" ::: "memory");
  __builtin_amdgcn_s_barrier();
  asm volatile("" ::: "memory");
}

// ---------------- transpose + cast: W[K][N] fp32 -> WT[N][K] fp16 ----------------
__global__ void k_transcvt(const float* __restrict__ in, _Float16* __restrict__ out, int N, int K) {
  __shared__ float tile[64 * 65];
  int tn = blockIdx.x * 64, tk = blockIdx.y * 64;
  for (int i = 0; i < 4; ++i) {
    int cid = i * 256 + threadIdx.x;     // 1024 chunks of 4 floats
    int r = cid >> 4, c4 = cid & 15;
    float4 v = *(const float4*)(in + (size_t)(tk + r) * N + tn + c4 * 4);
    tile[r * 65 + c4 * 4 + 0] = v.x; tile[r * 65 + c4 * 4 + 1] = v.y;
    tile[r * 65 + c4 * 4 + 2] = v.z; tile[r * 65 + c4 * 4 + 3] = v.w;
  }
  __syncthreads();
  for (int i = 0; i < 2; ++i) {
    int cid = i * 256 + threadIdx.x;     // 512 chunks of 8 fp16
    int n = cid >> 3, kc = cid & 7;
    h8 o;
    for (int j = 0; j < 8; ++j) o[j] = (_Float16)tile[(kc * 8 + j) * 65 + n];
    *(h8*)(out + (size_t)(tn + n) * K + tk + kc * 8) = o;
  }
}

// ================= 256x256 8-phase tile loop (BK=64, K=1024), seam-capable =================
// 8 waves (2M x 4N), per-wave output 128x64, double-buffered 128 KiB LDS.
// A32=true: A read as fp32 from HBM, reg-staged (4x dwordx4 -> 16x RNE cvt ->
//   2x ds_write_b128 per half). vmcnt FIFO per iter: [B(u+1):4, A-regs:8,
//   B(u+2):4] -> the standard vmcnt(4) at phase 4 drains B(u+1)+A-regs; cvt +
//   ds_write placed after the MFMA block (VALU overlaps MFMA pipe), lgkmcnt(0)
//   before the phase-end barrier for cross-wave visibility.
// Seam mode (more=true): u=14/15 staging redirects to next tile's B(0),B(64),A(0);
// pipeline never drains across tiles; only the last tile drains vmcnt(0).
template <bool A32>
__device__ __forceinline__ void gemm256_tile(
    const _Float16* __restrict__ Ab, const float* __restrict__ Af,
    const _Float16* __restrict__ Bb, const _Float16* __restrict__ BbN,
    bool first, bool more, char* smem, f4 (&acc)[8][4]) {
  constexpr int TILE = 32768, HALF = 16384;
  int tid = threadIdx.x, lane = tid & 63, wave = tid >> 6;
  int l15 = lane & 15, l4 = lane >> 4;
  int wm = (wave >> 2) * 128, wn = (wave & 3) * 64;
  int rs = tid >> 3, cg = (tid & 7) ^ (rs & 7);
  char* cA = smem;            char* nA = smem + TILE;
  char* cB = smem + 2 * TILE; char* nB = smem + 3 * TILE;

  auto stA16 = [&](int kt, int h, char* dst) {
    const _Float16* s = Ab + (size_t)(h * 128 + rs) * 1024 + kt + cg * 8;
    gl_lds16(s, dst + h * HALF + tid * 16);
    gl_lds16(s + (size_t)64 * 1024, dst + h * HALF + 8192 + tid * 16);
  };
  auto ldA32 = [&](int kt, int h, float4 (&v)[4]) {
    const float* s = Af + (size_t)(h * 128 + rs) * 1024 + kt + cg * 8;
    v[0] = *(const float4*)(s);
    v[1] = *(const float4*)(s + 4);
    v[2] = *(const float4*)(s + (size_t)64 * 1024);
    v[3] = *(const float4*)(s + (size_t)64 * 1024 + 4);
  };
  auto wrA32 = [&](char* dst, int h, float4 (&v)[4]) {
    h8 o0, o1;
    o0[0] = (_Float16)v[0].x; o0[1] = (_Float16)v[0].y;
    o0[2] = (_Float16)v[0].z; o0[3] = (_Float16)v[0].w;
    o0[4] = (_Float16)v[1].x; o0[5] = (_Float16)v[1].y;
    o0[6] = (_Float16)v[1].z; o0[7] = (_Float16)v[1].w;
    o1[0] = (_Float16)v[2].x; o1[1] = (_Float16)v[2].y;
    o1[2] = (_Float16)v[2].z; o1[3] = (_Float16)v[2].w;
    o1[4] = (_Float16)v[3].x; o1[5] = (_Float16)v[3].y;
    o1[6] = (_Float16)v[3].z; o1[7] = (_Float16)v[3].w;
    *(h8*)(dst + h * HALF + tid * 16) = o0;
    *(h8*)(dst + h * HALF + 8192 + tid * 16) = o1;
  };
  auto stB = [&](const _Float16* base, int kt, int h, char* dst) {
    const _Float16* s = base + (size_t)(h * 128 + rs) * 1024 + kt + cg * 8;
    gl_lds16(s, dst + h * HALF + tid * 16);
    gl_lds16(s + (size_t)64 * 1024, dst + h * HALF + 8192 + tid * 16);
  };

  float4 a0[4], a1[4];

  if (first) {
    if constexpr (A32) {
      ldA32(0, 0, a0); ldA32(0, 1, a1);          // 8 loads (oldest)
      stB(Bb, 0, 0, cB); stB(Bb, 0, 1, cB);      // 4
      stB(Bb, 64, 0, nB); stB(Bb, 64, 1, nB);    // 4
      asm volatile("s_waitcnt vmcnt(8)" ::: "memory");   // A0 landed
      wrA32(cA, 0, a0); wrA32(cA, 1, a1);
      asm volatile("s_waitcnt lgkmcnt(0)" ::: "memory");
      asm volatile("s_waitcnt vmcnt(4)" ::: "memory");   // B(0) landed; B(64) in flight
    } else {
      stA16(0, 0, cA); stA16(0, 1, cA);
      stB(Bb, 0, 0, cB); stB(Bb, 0, 1, cB);
      stB(Bb, 64, 0, nB); stB(Bb, 64, 1, nB);
      asm volatile("s_waitcnt vmcnt(4)" ::: "memory");
    }
    BAR();
  }

  h8 af[4][2], bf[4][2];
  for (int u = 0; u < 16; ++u) {
    int kt1 = (u + 1) << 6, kt2 = (u + 2) << 6;
    bool stage_a = (u < 15) || more;
    int akt = (u < 15) ? kt1 : 0;
    // ---- phase 1: (Mh0, Nh0); 12 ds_reads; issue A.h0 (kt1, or next-tile kt0 at u=15)
#pragma unroll
    for (int mi = 0; mi < 4; ++mi) {
      int r = wm + mi * 16 + l15;
      af[mi][0] = lds_frag(cA, r, l4);
      af[mi][1] = lds_frag(cA, r, 4 + l4);
    }
#pragma unroll
    for (int nj = 0; nj < 2; ++nj) {
      int r = wn + nj * 16 + l15;
      bf[nj][0] = lds_frag(cB, r, l4);
      bf[nj][1] = lds_frag(cB, r, 4 + l4);
    }
    if (stage_a) {
      if constexpr (A32) ldA32(akt, 0, a0);
      else stA16(akt, 0, nA);
    }
    asm volatile("s_waitcnt lgkmcnt(8)" ::: "memory");
    BAR();
    asm volatile("s_waitcnt lgkmcnt(0)" ::: "memory");
    __builtin_amdgcn_s_setprio(1);
#pragma unroll
    for (int kk = 0; kk < 2; ++kk)
#pragma unroll
      for (int mi = 0; mi < 4; ++mi)
#pragma unroll
        for (int nj = 0; nj < 2; ++nj)
          acc[mi][nj] = MFMA(af[mi][kk], bf[nj][kk], acc[mi][nj]);
    __builtin_amdgcn_s_setprio(0);
    BAR();
    // ---- phase 2: (Mh0, Nh1); issue A.h1
#pragma unroll
    for (int nj = 2; nj < 4; ++nj) {
      int r = wn + nj * 16 + l15;
      bf[nj][0] = lds_frag(cB, r, l4);
      bf[nj][1] = lds_frag(cB, r, 4 + l4);
    }
    if (stage_a) {
      if constexpr (A32) ldA32(akt, 1, a1);
      else stA16(akt, 1, nA);
    }
    BAR();
    asm volatile("s_waitcnt lgkmcnt(0)" ::: "memory");
    __builtin_amdgcn_s_setprio(1);
#pragma unroll
    for (int kk = 0; kk < 2; ++kk)
#pragma unroll
      for (int mi = 0; mi < 4; ++mi)
#pragma unroll
        for (int nj = 2; nj < 4; ++nj)
          acc[mi][nj] = MFMA(af[mi][kk], bf[nj][kk], acc[mi][nj]);
    __builtin_amdgcn_s_setprio(0);
    BAR();
    // ---- phase 3: (Mh1, Nh1); stage B.h0 (kt2, or next-tile kt0/kt64 at u=14/15)
#pragma unroll
    for (int mi = 0; mi < 4; ++mi) {
      int r = wm + 64 + mi * 16 + l15;
      af[mi][0] = lds_frag(cA, r, l4);
      af[mi][1] = lds_frag(cA, r, 4 + l4);
    }
    if (u < 14) stB(Bb, kt2, 0, cB);
    else if (more) stB(BbN, (u == 14) ? 0 : 64, 0, cB);
    BAR();
    asm volatile("s_waitcnt lgkmcnt(0)" ::: "memory");
    __builtin_amdgcn_s_setprio(1);
#pragma unroll
    for (int kk = 0; kk < 2; ++kk)
#pragma unroll
      for (int mi = 0; mi < 4; ++mi)
#pragma unroll
        for (int nj = 2; nj < 4; ++nj)
          acc[4 + mi][nj] = MFMA(af[mi][kk], bf[nj][kk], acc[4 + mi][nj]);
    __builtin_amdgcn_s_setprio(0);
    BAR();
    // ---- phase 4: (Mh1, Nh0); stage B.h1; counted vmcnt; A cvt+write after MFMA
    if (u < 14) stB(Bb, kt2, 1, cB);
    else if (more) stB(BbN, (u == 14) ? 0 : 64, 1, cB);
    if (u < 14 || more) asm volatile("s_waitcnt vmcnt(4)" ::: "memory");  // drains B(u+1)+A-regs
    else                asm volatile("s_waitcnt vmcnt(0)" ::: "memory");  // tail drain
    BAR();
    __builtin_amdgcn_s_setprio(1);
#pragma unroll
    for (int kk = 0; kk < 2; ++kk)
#pragma unroll
      for (int mi = 0; mi < 4; ++mi)
#pragma unroll
        for (int nj = 0; nj < 2; ++nj)
          acc[4 + mi][nj] = MFMA(af[mi][kk], bf[nj][kk], acc[4 + mi][nj]);
    __builtin_amdgcn_s_setprio(0);
    if constexpr (A32) {
      if (stage_a) {
        wrA32(nA, 0, a0); wrA32(nA, 1, a1);
        asm volatile("s_waitcnt lgkmcnt(0)" ::: "memory");
      }
    }
    BAR();
    char* t = cA; cA = nA; nA = t;
    t = cB; cB = nB; nB = t;
  }
}

// ---------------- GEMM1 (persistent, fused fp32-A): qkv = hs(16384x1024 f32) @ wqkvT^T ----------------
// 256 blocks = 1/CU. Each block owns one 256-row A panel (converted on the fly)
// and processes Q-col, K-col, V-col tiles back-to-back with seam staging.
__global__ __launch_bounds__(512) void k_gemm_qkv(
    const float* __restrict__ A32, const _Float16* __restrict__ BT,
    const float* __restrict__ bias,
    _Float16* __restrict__ Q, _Float16* __restrict__ Kq, _Float16* __restrict__ Vt) {
  __shared__ char smem[131072];
  int id = blockIdx.x;                        // 256 blocks
  int swz = (id & 7) * 32 + (id >> 3);        // XCD-chunked
  int by = swz >> 2, c = swz & 3;
  int tm = by * 256;
  const float* Af = A32 + (size_t)tm * 1024;
  int tid = threadIdx.x, lane = tid & 63, wave = tid >> 6;
  int l15 = lane & 15, l4 = lane >> 4;
  int wm = (wave >> 2) * 128, wn = (wave & 3) * 64;

  for (int t = 0; t < 3; ++t) {
    int tn = (t * 4 + c) * 256;
    const _Float16* Bb = BT + (size_t)tn * 1024;
    const _Float16* BbN = Bb + (size_t)1024 * 1024;   // next tile's B panel (tn+1024)
    f4 acc[8][4] = {};
    gemm256_tile<true>(nullptr, Af, Bb, BbN, t == 0, t < 2, smem, acc);

    if (t < 2) {
      // Q / K scatter (no LDS; stores drain under next tile's first iters).
      _Float16* dst = (t == 0) ? Q : Kq;
#pragma unroll
      for (int nj = 0; nj < 4; ++nj) {
        int n = tn + wn + nj * 16 + l15;
        float bv = bias[n];
        int h = (n >> 6) & 15, d = n & 63;
#pragma unroll
        for (int mig = 0; mig < 8; ++mig) {
#pragma unroll
          for (int r = 0; r < 4; ++r) {
            int m = tm + wm + mig * 16 + l4 * 4 + r;
            int b = m >> 10, tt = m & 1023;
            dst[(((size_t)b * 16 + h) * 1024 + tt) * 64 + d] =
                (_Float16)(acc[mig][nj][r] + bv);
          }
        }
      }
    } else {
      // V path (last tile; LDS free): transpose 256t x 256n tile to Vt[bh][d][t]
      _Float16* L = (_Float16*)smem;           // [128][264] fp16 = 67584 B
      int b = tm >> 10, tb = tm & 1023;
#pragma unroll
      for (int p = 0; p < 2; ++p) {
        __syncthreads();
        if (((wave >> 1) & 1) == p) {          // waves with warp_n in {2p, 2p+1}
          int nloc = (wave & 1) * 64;
#pragma unroll
          for (int nj = 0; nj < 4; ++nj) {
            int nl = nloc + nj * 16 + l15;
            float bv = bias[tn + p * 128 + nl];
#pragma unroll
            for (int mig = 0; mig < 8; ++mig) {
              h4 pk;
#pragma unroll
              for (int r = 0; r < 4; ++r) pk[r] = (_Float16)(acc[mig][nj][r] + bv);
              *(h4*)(L + nl * 264 + wm + mig * 16 + l4 * 4) = pk;
            }
          }
        }
        __syncthreads();
#pragma unroll
        for (int i = 0; i < 8; ++i) {
          int cid = i * 512 + tid;
          int nl = cid >> 5, tc = cid & 31;
          int ng = tn + p * 128 + nl;
          int h = (ng >> 6) & 15, d = ng & 63;
          *(h8*)(Vt + (((size_t)b * 16 + h) * 64 + d) * 1024 + tb + tc * 8) =
              *(const h8*)(L + nl * 264 + tc * 8);
        }
      }
    }
  }
}

// ---------------- flash attention: 256-q tile, 64q/wave, K/V double-buffered prefetch ----------------
// Q,K [BH][1024][64], Vt [BH][64][1024] -> O [16384][1024] fp16
// launch_bounds(256,2): (256,3) forced ~170-reg cap -> 154 MB scratch spill (round-2).
__global__ __launch_bounds__(256, 2) void k_attn(
    const _Float16* __restrict__ Q, const _Float16* __restrict__ Kk,
    const _Float16* __restrict__ Vt, _Float16* __restrict__ O) {
  // sP: 4 waves * 64q * 40 * 2B = 20480 B ; K/V double-buffer: 2 * (8192 K + 8192 V)
  __shared__ char smem[20480 + 32768];
  _Float16* sP = (_Float16*)smem;
  char* sKV = smem + 20480;
  const float SCL = 0.125f * 1.44269504088896340736f;  // scale * log2(e)
  int tid = threadIdx.x, wave = tid >> 6, lane = tid & 63;
  int l15 = lane & 15, l4 = lane >> 4;
  int bh = blockIdx.y;
  int qt = blockIdx.x * 256;
  const _Float16* Qb = Q + (size_t)bh * 65536;
  const _Float16* Kb = Kk + (size_t)bh * 65536;
  const _Float16* Vb = Vt + (size_t)bh * 65536;

  // B-operand Q fragments for this wave's 64 queries, direct from global, pre-scaled
  h8 qf[4][2];
#pragma unroll
  for (int nt = 0; nt < 4; ++nt) {
    int r = qt + wave * 64 + nt * 16 + l15;
#pragma unroll
    for (int kk = 0; kk < 2; ++kk)
      qf[nt][kk] = *(const h8*)(Qb + (size_t)r * 64 + (kk * 4 + l4) * 8);
  }
  _Float16 scl_h = (_Float16)SCL;
#pragma unroll
  for (int nt = 0; nt < 4; ++nt)
#pragma unroll
    for (int kk = 0; kk < 2; ++kk)
#pragma unroll
      for (int j = 0; j < 8; ++j) qf[nt][kk][j] *= scl_h;

  // hoisted staging addresses
  int cid0 = tid, cid1 = tid + 256;
  int r0 = cid0 >> 3, c0 = (cid0 & 7) ^ (r0 & 7);
  int r1 = cid1 >> 3, c1 = (cid1 & 7) ^ (r1 & 7);
  const _Float16* kp0 = Kb + (size_t)r0 * 64 + c0 * 8;
  const _Float16* kp1 = Kb + (size_t)r1 * 64 + c1 * 8;
  const _Float16* vp0 = Vb + (size_t)r0 * 1024 + c0 * 8;
  const _Float16* vp1 = Vb + (size_t)r1 * 1024 + c1 * 8;

  auto stage = [&](int it, int b) {
    char* dK = sKV + b * 16384;
    char* dV = dK + 8192;
    size_t ko = (size_t)it * 4096;   // 64 keys forward
    size_t vo = (size_t)it * 64;     // 64 t forward
    gl_lds16(kp0 + ko, dK + cid0 * 16);
    gl_lds16(kp1 + ko, dK + cid1 * 16);
    gl_lds16(vp0 + vo, dV + cid0 * 16);
    gl_lds16(vp1 + vo, dV + cid1 * 16);
  };

  f4 oacc[4][4] = {};
  f4 lacc[4] = {};
  h8 ones;
#pragma unroll
  for (int j = 0; j < 8; ++j) ones[j] = (_Float16)1.0f;
  _Float16* pw = sP + wave * 64 * 40;

  stage(0, 0);
  asm volatile("s_waitcnt vmcnt(0)" ::: "memory");
  BAR();

  for (int it = 0; it < 16; ++it) {
    int cur = it & 1;
    if (it < 15) stage(it + 1, cur ^ 1);          // prefetch next tile (hidden under compute)
    const char* sK = sKV + cur * 16384;
    const char* sV = sK + 8192;
    for (int mh = 0; mh < 2; ++mh) {
      // S^T = K . Q^T for this 32-key half
      f4 sacc[2][4] = {};
#pragma unroll
      for (int kk = 0; kk < 2; ++kk) {
        h8 kf[2];
        int ch = kk * 4 + l4;
#pragma unroll
        for (int mt = 0; mt < 2; ++mt) {
          int r = mh * 32 + mt * 16 + l15;
          kf[mt] = *(const h8*)(sK + ((r * 8 + (ch ^ (r & 7))) * 16));
        }
#pragma unroll
        for (int mt = 0; mt < 2; ++mt)
#pragma unroll
          for (int nt = 0; nt < 4; ++nt)
            sacc[mt][nt] = MFMA(kf[mt], qf[nt][kk], sacc[mt][nt]);
      }
      // exp2 (raw v_exp_f32; args bounded) + pkrtz pack, write P-half (stride 40 fp16)
#pragma unroll
      for (int mt = 0; mt < 2; ++mt) {
#pragma unroll
        for (int nt = 0; nt < 4; ++nt) {
          float p0 = __builtin_amdgcn_exp2f(sacc[mt][nt][0]);
          float p1 = __builtin_amdgcn_exp2f(sacc[mt][nt][1]);
          float p2 = __builtin_amdgcn_exp2f(sacc[mt][nt][2]);
          float p3 = __builtin_amdgcn_exp2f(sacc[mt][nt][3]);
          union { fp16x2 h[2]; h4 v; } uu;
          uu.h[0] = __builtin_amdgcn_cvt_pkrtz(p0, p1);
          uu.h[1] = __builtin_amdgcn_cvt_pkrtz(p2, p3);
          *(h4*)(pw + (nt * 16 + l15) * 40 + mt * 16 + l4 * 4) = uu.v;
        }
      }
      // PV for this half (k=32 = one MFMA K); row sums via ones-MFMA
      h8 pf[4], vf[4];
#pragma unroll
      for (int mi = 0; mi < 4; ++mi)
        pf[mi] = *(const h8*)(pw + (mi * 16 + l15) * 40 + l4 * 8);
      int ch = mh * 4 + l4;
#pragma unroll
      for (int nd = 0; nd < 4; ++nd) {
        int r = nd * 16 + l15;
        vf[nd] = *(const h8*)(sV + ((r * 8 + (ch ^ (r & 7))) * 16));
      }
#pragma unroll
      for (int mi = 0; mi < 4; ++mi) {
#pragma unroll
        for (int nd = 0; nd < 4; ++nd)
          oacc[mi][nd] = MFMA(pf[mi], vf[nd], oacc[mi][nd]);
        lacc[mi] = MFMA(pf[mi], ones, lacc[mi]);
      }
    }
    // vmcnt(0): prefetch landed. (sP is per-wave private; no lgkm drain needed at barrier)
    asm volatile("s_waitcnt vmcnt(0)" ::: "memory");
    BAR();
  }
  // normalize + write (row sum already per-lane in lacc, C-layout aligned with oacc)
  int b = bh >> 4, h = bh & 15;
#pragma unroll
  for (int mi = 0; mi < 4; ++mi) {
#pragma unroll
    for (int r = 0; r < 4; ++r) {
      float inv = 1.f / lacc[mi][r];
      int t = qt + wave * 64 + mi * 16 + l4 * 4 + r;
#pragma unroll
      for (int nd = 0; nd < 4; ++nd)
        O[(size_t)(b * 1024 + t) * 1024 + h * 64 + nd * 16 + l15] =
            (_Float16)(oacc[mi][nd][r] * inv);
    }
  }
}

// ---------------- GEMM2: out = attn(16384x1024) @ woutT(1024x1024)^T + b, fp32 out ----------------
__global__ __launch_bounds__(512) void k_gemm_out(
    const _Float16* __restrict__ A, const _Float16* __restrict__ BT,
    const float* __restrict__ bias, float* __restrict__ C) {
  __shared__ char smem[131072];
  int id = blockIdx.x;                        // 256 blocks, 256 % 8 == 0
  int swz = (id & 7) * 32 + (id >> 3);
  int by = swz >> 2, bx = swz & 3;
  int tm = by * 256, tn = bx * 256;
  f4 acc[8][4] = {};
  gemm256_tile<false>(A + (size_t)tm * 1024, nullptr, BT + (size_t)tn * 1024,
                      nullptr, true, false, smem, acc);

  int tid = threadIdx.x, lane = tid & 63, wave = tid >> 6;
  int l15 = lane & 15, l4 = lane >> 4;
  int wm = (wave >> 2) * 128, wn = (wave & 3) * 64;
#pragma unroll
  for (int nj = 0; nj < 4; ++nj) {
    int n = tn + wn + nj * 16 + l15;
    float bv = bias[n];
#pragma unroll
    for (int mig = 0; mig < 8; ++mig) {
#pragma unroll
      for (int r = 0; r < 4; ++r) {
        int m = tm + wm + mig * 16 + l4 * 4 + r;
        C[(size_t)m * 1024 + n] = acc[mig][nj][r] + bv;
      }
    }
  }
}

extern "C" void kernel_launch(void* const* d_in, const int* in_sizes, int n_in,
                              void* d_out, int out_size, void* d_ws, size_t ws_size,
                              hipStream_t stream) {
  const float* hs    = (const float*)d_in[0];
  const float* w_qkv = (const float*)d_in[1];
  const float* b_qkv = (const float*)d_in[2];
  const float* w_out = (const float*)d_in[3];
  const float* b_out = (const float*)d_in[4];
  float* out = (float*)d_out;
  char* ws = (char*)d_ws;

  _Float16* attn_h = (_Float16*)(ws);                         // 33,554,432 B (attn out)
  _Float16* wqkvT = (_Float16*)(ws + 33554432);               //  6,291,456 B
  _Float16* woutT = (_Float16*)(ws + 39845888);               //  2,097,152 B
  _Float16* q_ws  = (_Float16*)(ws + 41943040);               // 33,554,432 B
  _Float16* k_ws  = (_Float16*)(ws + 75497472);               // 33,554,432 B
  _Float16* vt_ws = (_Float16*)(ws + 109051904);              // 33,554,432 B (V, transposed)

  k_transcvt<<<dim3(48, 16), 256, 0, stream>>>(w_qkv, wqkvT, 3072, 1024);
  k_transcvt<<<dim3(16, 16), 256, 0, stream>>>(w_out, woutT, 1024, 1024);
  k_gemm_qkv<<<256, 512, 0, stream>>>(hs, wqkvT, b_qkv, q_ws, k_ws, vt_ws);
  k_attn<<<dim3(4, 256), 256, 0, stream>>>(q_ws, k_ws, vt_ws, attn_h);
  k_gemm_out<<<256, 512, 0, stream>>>(attn_h, woutT, b_out, out);
}

// Round 9
// 358.440 us; speedup vs baseline: 1.1554x; 1.1554x over previous
//
#include <hip/hip_runtime.h>
#include <cstdint>
#include <cstddef>

typedef _Float16 h8 __attribute__((ext_vector_type(8)));
typedef _Float16 h4 __attribute__((ext_vector_type(4)));
typedef __fp16 fp16x2 __attribute__((ext_vector_type(2)));
typedef float f4 __attribute__((ext_vector_type(4)));

#define MFMA(a, b, c) __builtin_amdgcn_mfma_f32_16x16x32_f16((a), (b), (c), 0, 0, 0)

__device__ __forceinline__ void gl_lds16(const void* g, void* l) {
  __builtin_amdgcn_global_load_lds((const __attribute__((address_space(1))) void*)g,
                                   (__attribute__((address_space(3))) void*)l, 16, 0, 0);
}

// swizzled LDS fragment read: row r, 16B chunk ch, 8 chunks per 64-f16 row
__device__ __forceinline__ h8 lds_frag(const char* base, int r, int ch) {
  return *(const h8*)(base + ((r * 8 + (ch ^ (r & 7))) * 16));
}

// barrier with compile-time memory fences on both sides (no LDS op may cross)
__device__ __forceinline__ void BAR() {
  asm volatile("" ::: "memory");
  __builtin_amdgcn_s_barrier();
  asm volatile("" ::: "memory");
}

// ---------------- fused preprocessing: hs fp32->fp16 + both weight transposes ----------------
// blocks [0,8192): cvt hs (16384x1024 f32 -> f16, 8 elems/thread)
// blocks [8192,8960): transcvt w_qkv (N=3072), [8960,9216): transcvt w_out (N=1024)
__global__ void k_pre(const float* __restrict__ hs, _Float16* __restrict__ hs_h,
                      const float* __restrict__ w_qkv, _Float16* __restrict__ wqkvT,
                      const float* __restrict__ w_out, _Float16* __restrict__ woutT) {
  int id = blockIdx.x;
  if (id < 8192) {
    size_t idx = ((size_t)id * 256 + threadIdx.x) * 8;   // 8192*256*8 = 16M exact
    float4 a = *(const float4*)(hs + idx);
    float4 b = *(const float4*)(hs + idx + 4);
    h8 o;
    o[0] = (_Float16)a.x; o[1] = (_Float16)a.y; o[2] = (_Float16)a.z; o[3] = (_Float16)a.w;
    o[4] = (_Float16)b.x; o[5] = (_Float16)b.y; o[6] = (_Float16)b.z; o[7] = (_Float16)b.w;
    *(h8*)(hs_h + idx) = o;
    return;
  }
  __shared__ float tile[64 * 65];
  const float* in; _Float16* out; int N, bx, by;
  if (id < 8960) { int t = id - 8192; in = w_qkv; out = wqkvT; N = 3072; bx = t % 48; by = t / 48; }
  else           { int t = id - 8960; in = w_out; out = woutT; N = 1024; bx = t & 15; by = t >> 4; }
  const int K = 1024;
  int tn = bx * 64, tk = by * 64;
  for (int i = 0; i < 4; ++i) {
    int cid = i * 256 + threadIdx.x;     // 1024 chunks of 4 floats
    int r = cid >> 4, c4 = cid & 15;
    float4 v = *(const float4*)(in + (size_t)(tk + r) * N + tn + c4 * 4);
    tile[r * 65 + c4 * 4 + 0] = v.x; tile[r * 65 + c4 * 4 + 1] = v.y;
    tile[r * 65 + c4 * 4 + 2] = v.z; tile[r * 65 + c4 * 4 + 3] = v.w;
  }
  __syncthreads();
  for (int i = 0; i < 2; ++i) {
    int cid = i * 256 + threadIdx.x;     // 512 chunks of 8 fp16
    int n = cid >> 3, kc = cid & 7;
    h8 o;
    for (int j = 0; j < 8; ++j) o[j] = (_Float16)tile[(kc * 8 + j) * 65 + n];
    *(h8*)(out + (size_t)(tn + n) * K + tk + kc * 8) = o;
  }
}

// ================= 256x256 8-phase tile loop (BK=64, K=1024), seam-capable =================
// 8 waves (2M x 4N), per-wave output 128x64, double-buffered 128 KiB LDS.
// 4 phases per K-tile; counted vmcnt(4) once per K-tile.
// Seam mode (more=true): u=14/15's staging slots redirect to the NEXT tile's
// B(kt0), B(kt64) and A(kt0); pipeline never drains across tiles.
// (Round-8 lesson: A reg-staging fp32-fused REGRESSED 124->200 us -- the phase-4
// vmcnt then waits on same-iteration A loads, collapsing pipeline depth. Keep
// the separate fp16 pre-convert + global_load_lds staging.)
__device__ __forceinline__ void gemm256_tile(
    const _Float16* __restrict__ Ab, const _Float16* __restrict__ Bb,
    const _Float16* __restrict__ BbN, bool first, bool more,
    char* smem, f4 (&acc)[8][4]) {
  constexpr int TILE = 32768, HALF = 16384;
  int tid = threadIdx.x, lane = tid & 63, wave = tid >> 6;
  int l15 = lane & 15, l4 = lane >> 4;
  int wm = (wave >> 2) * 128, wn = (wave & 3) * 64;
  int rs = tid >> 3, cg = (tid & 7) ^ (rs & 7);
  char* cA = smem;            char* nA = smem + TILE;
  char* cB = smem + 2 * TILE; char* nB = smem + 3 * TILE;

  auto stA = [&](int kt, int h, char* dst) {
    const _Float16* s = Ab + (size_t)(h * 128 + rs) * 1024 + kt + cg * 8;
    gl_lds16(s, dst + h * HALF + tid * 16);
    gl_lds16(s + (size_t)64 * 1024, dst + h * HALF + 8192 + tid * 16);
  };
  auto stB = [&](const _Float16* base, int kt, int h, char* dst) {
    const _Float16* s = base + (size_t)(h * 128 + rs) * 1024 + kt + cg * 8;
    gl_lds16(s, dst + h * HALF + tid * 16);
    gl_lds16(s + (size_t)64 * 1024, dst + h * HALF + 8192 + tid * 16);
  };

  if (first) {
    // cold prologue: tile0 A+B -> buf0; tile0 B(64) -> buf1
    stA(0, 0, cA); stA(0, 1, cA);
    stB(Bb, 0, 0, cB); stB(Bb, 0, 1, cB);
    stB(Bb, 64, 0, nB); stB(Bb, 64, 1, nB);
    asm volatile("s_waitcnt vmcnt(4)" ::: "memory");
    BAR();
  }

  h8 af[4][2], bf[4][2];
  for (int u = 0; u < 16; ++u) {
    int kt1 = (u + 1) << 6, kt2 = (u + 2) << 6;
    // ---- phase 1: (Mh0, Nh0); 12 ds_reads; stage A.h0 (kt1, or next-tile kt0 at u=15)
#pragma unroll
    for (int mi = 0; mi < 4; ++mi) {
      int r = wm + mi * 16 + l15;
      af[mi][0] = lds_frag(cA, r, l4);
      af[mi][1] = lds_frag(cA, r, 4 + l4);
    }
#pragma unroll
    for (int nj = 0; nj < 2; ++nj) {
      int r = wn + nj * 16 + l15;
      bf[nj][0] = lds_frag(cB, r, l4);
      bf[nj][1] = lds_frag(cB, r, 4 + l4);
    }
    if (u < 15) stA(kt1, 0, nA);
    else if (more) stA(0, 0, nA);
    asm volatile("s_waitcnt lgkmcnt(8)" ::: "memory");
    BAR();
    asm volatile("s_waitcnt lgkmcnt(0)" ::: "memory");
    __builtin_amdgcn_s_setprio(1);
#pragma unroll
    for (int kk = 0; kk < 2; ++kk)
#pragma unroll
      for (int mi = 0; mi < 4; ++mi)
#pragma unroll
        for (int nj = 0; nj < 2; ++nj)
          acc[mi][nj] = MFMA(af[mi][kk], bf[nj][kk], acc[mi][nj]);
    __builtin_amdgcn_s_setprio(0);
    BAR();
    // ---- phase 2: (Mh0, Nh1); stage A.h1
#pragma unroll
    for (int nj = 2; nj < 4; ++nj) {
      int r = wn + nj * 16 + l15;
      bf[nj][0] = lds_frag(cB, r, l4);
      bf[nj][1] = lds_frag(cB, r, 4 + l4);
    }
    if (u < 15) stA(kt1, 1, nA);
    else if (more) stA(0, 1, nA);
    BAR();
    asm volatile("s_waitcnt lgkmcnt(0)" ::: "memory");
    __builtin_amdgcn_s_setprio(1);
#pragma unroll
    for (int kk = 0; kk < 2; ++kk)
#pragma unroll
      for (int mi = 0; mi < 4; ++mi)
#pragma unroll
        for (int nj = 2; nj < 4; ++nj)
          acc[mi][nj] = MFMA(af[mi][kk], bf[nj][kk], acc[mi][nj]);
    __builtin_amdgcn_s_setprio(0);
    BAR();
    // ---- phase 3: (Mh1, Nh1); stage B.h0 (kt2, or next-tile kt0/kt64 at u=14/15)
#pragma unroll
    for (int mi = 0; mi < 4; ++mi) {
      int r = wm + 64 + mi * 16 + l15;
      af[mi][0] = lds_frag(cA, r, l4);
      af[mi][1] = lds_frag(cA, r, 4 + l4);
    }
    if (u < 14) stB(Bb, kt2, 0, cB);
    else if (more) stB(BbN, (u == 14) ? 0 : 64, 0, cB);
    BAR();
    asm volatile("s_waitcnt lgkmcnt(0)" ::: "memory");
    __builtin_amdgcn_s_setprio(1);
#pragma unroll
    for (int kk = 0; kk < 2; ++kk)
#pragma unroll
      for (int mi = 0; mi < 4; ++mi)
#pragma unroll
        for (int nj = 2; nj < 4; ++nj)
          acc[4 + mi][nj] = MFMA(af[mi][kk], bf[nj][kk], acc[4 + mi][nj]);
    __builtin_amdgcn_s_setprio(0);
    BAR();
    // ---- phase 4: (Mh1, Nh0); stage B.h1; counted vmcnt (drain only on last tile)
    if (u < 14) stB(Bb, kt2, 1, cB);
    else if (more) stB(BbN, (u == 14) ? 0 : 64, 1, cB);
    if (u < 14 || more) asm volatile("s_waitcnt vmcnt(4)" ::: "memory");
    else                asm volatile("s_waitcnt vmcnt(0)" ::: "memory");
    BAR();
    __builtin_amdgcn_s_setprio(1);
#pragma unroll
    for (int kk = 0; kk < 2; ++kk)
#pragma unroll
      for (int mi = 0; mi < 4; ++mi)
#pragma unroll
        for (int nj = 0; nj < 2; ++nj)
          acc[4 + mi][nj] = MFMA(af[mi][kk], bf[nj][kk], acc[4 + mi][nj]);
    __builtin_amdgcn_s_setprio(0);
    BAR();
    char* t = cA; cA = nA; nA = t;
    t = cB; cB = nB; nB = t;
  }
}

// ---------------- GEMM1 (persistent): qkv = hs_h(16384x1024) @ wqkvT(3072x1024)^T ----------------
// 256 blocks = 1/CU. Each block owns one 256-row A panel; Q-col, K-col, V-col
// tiles back-to-back with seam staging (no pipeline drain between tiles).
__global__ __launch_bounds__(512) void k_gemm_qkv(
    const _Float16* __restrict__ A, const _Float16* __restrict__ BT,
    const float* __restrict__ bias,
    _Float16* __restrict__ Q, _Float16* __restrict__ Kq, _Float16* __restrict__ Vt) {
  __shared__ char smem[131072];
  int id = blockIdx.x;                        // 256 blocks
  int swz = (id & 7) * 32 + (id >> 3);        // XCD-chunked
  int by = swz >> 2, c = swz & 3;
  int tm = by * 256;
  const _Float16* Ab = A + (size_t)tm * 1024;
  int tid = threadIdx.x, lane = tid & 63, wave = tid >> 6;
  int l15 = lane & 15, l4 = lane >> 4;
  int wm = (wave >> 2) * 128, wn = (wave & 3) * 64;

  for (int t = 0; t < 3; ++t) {
    int tn = (t * 4 + c) * 256;
    const _Float16* Bb = BT + (size_t)tn * 1024;
    const _Float16* BbN = Bb + (size_t)1024 * 1024;   // next tile's B panel (tn+1024)
    f4 acc[8][4] = {};
    gemm256_tile(Ab, Bb, BbN, t == 0, t < 2, smem, acc);

    if (t < 2) {
      // Q / K scatter (no LDS; stores drain under next tile's first iters).
      _Float16* dst = (t == 0) ? Q : Kq;
#pragma unroll
      for (int nj = 0; nj < 4; ++nj) {
        int n = tn + wn + nj * 16 + l15;
        float bv = bias[n];
        int h = (n >> 6) & 15, d = n & 63;
#pragma unroll
        for (int mig = 0; mig < 8; ++mig) {
#pragma unroll
          for (int r = 0; r < 4; ++r) {
            int m = tm + wm + mig * 16 + l4 * 4 + r;
            int b = m >> 10, tt = m & 1023;
            dst[(((size_t)b * 16 + h) * 1024 + tt) * 64 + d] =
                (_Float16)(acc[mig][nj][r] + bv);
          }
        }
      }
    } else {
      // V path (last tile; LDS free): transpose 256t x 256n tile to Vt[bh][d][t]
      _Float16* L = (_Float16*)smem;           // [128][264] fp16 = 67584 B
      int b = tm >> 10, tb = tm & 1023;
#pragma unroll
      for (int p = 0; p < 2; ++p) {
        __syncthreads();
        if (((wave >> 1) & 1) == p) {          // waves with warp_n in {2p, 2p+1}
          int nloc = (wave & 1) * 64;
#pragma unroll
          for (int nj = 0; nj < 4; ++nj) {
            int nl = nloc + nj * 16 + l15;
            float bv = bias[tn + p * 128 + nl];
#pragma unroll
            for (int mig = 0; mig < 8; ++mig) {
              h4 pk;
#pragma unroll
              for (int r = 0; r < 4; ++r) pk[r] = (_Float16)(acc[mig][nj][r] + bv);
              *(h4*)(L + nl * 264 + wm + mig * 16 + l4 * 4) = pk;
            }
          }
        }
        __syncthreads();
#pragma unroll
        for (int i = 0; i < 8; ++i) {
          int cid = i * 512 + tid;
          int nl = cid >> 5, tc = cid & 31;
          int ng = tn + p * 128 + nl;
          int h = (ng >> 6) & 15, d = ng & 63;
          *(h8*)(Vt + (((size_t)b * 16 + h) * 64 + d) * 1024 + tb + tc * 8) =
              *(const h8*)(L + nl * 264 + tc * 8);
        }
      }
    }
  }
}

// ---------------- flash attention: 256-q tile, 64q/wave, 2-deep K/V prefetch ----------------
// Q,K [BH][1024][64], Vt [BH][64][1024] -> O [16384][1024] fp16
// 3 LDS K/V buffers (69.6 KB total, 2 blocks/CU); counted vmcnt(4) per iter
// (never drains to 0 in steady state): end-of-iter FIFO = [st(it+1):4, st(it+2):4].
// launch_bounds(256,2): (256,3) forced ~170-reg cap -> 154 MB scratch spill (round-2).
__global__ __launch_bounds__(256, 2) void k_attn(
    const _Float16* __restrict__ Q, const _Float16* __restrict__ Kk,
    const _Float16* __restrict__ Vt, _Float16* __restrict__ O) {
  // sP: 4 waves * 64q * 40 * 2B = 20480 B ; K/V triple-buffer: 3 * (8192 K + 8192 V)
  __shared__ char smem[20480 + 49152];
  _Float16* sP = (_Float16*)smem;
  char* sKV = smem + 20480;
  const float SCL = 0.125f * 1.44269504088896340736f;  // scale * log2(e)
  int tid = threadIdx.x, wave = tid >> 6, lane = tid & 63;
  int l15 = lane & 15, l4 = lane >> 4;
  int bh = blockIdx.y;
  int qt = blockIdx.x * 256;
  const _Float16* Qb = Q + (size_t)bh * 65536;
  const _Float16* Kb = Kk + (size_t)bh * 65536;
  const _Float16* Vb = Vt + (size_t)bh * 65536;

  // B-operand Q fragments for this wave's 64 queries, direct from global, pre-scaled
  h8 qf[4][2];
#pragma unroll
  for (int nt = 0; nt < 4; ++nt) {
    int r = qt + wave * 64 + nt * 16 + l15;
#pragma unroll
    for (int kk = 0; kk < 2; ++kk)
      qf[nt][kk] = *(const h8*)(Qb + (size_t)r * 64 + (kk * 4 + l4) * 8);
  }
  _Float16 scl_h = (_Float16)SCL;
#pragma unroll
  for (int nt = 0; nt < 4; ++nt)
#pragma unroll
    for (int kk = 0; kk < 2; ++kk)
#pragma unroll
      for (int j = 0; j < 8; ++j) qf[nt][kk][j] *= scl_h;

  // hoisted staging addresses
  int cid0 = tid, cid1 = tid + 256;
  int r0 = cid0 >> 3, c0 = (cid0 & 7) ^ (r0 & 7);
  int r1 = cid1 >> 3, c1 = (cid1 & 7) ^ (r1 & 7);
  const _Float16* kp0 = Kb + (size_t)r0 * 64 + c0 * 8;
  const _Float16* kp1 = Kb + (size_t)r1 * 64 + c1 * 8;
  const _Float16* vp0 = Vb + (size_t)r0 * 1024 + c0 * 8;
  const _Float16* vp1 = Vb + (size_t)r1 * 1024 + c1 * 8;

  auto stage = [&](int it, int b) {
    char* dK = sKV + b * 16384;
    char* dV = dK + 8192;
    size_t ko = (size_t)it * 4096;   // 64 keys forward
    size_t vo = (size_t)it * 64;     // 64 t forward
    gl_lds16(kp0 + ko, dK + cid0 * 16);
    gl_lds16(kp1 + ko, dK + cid1 * 16);
    gl_lds16(vp0 + vo, dV + cid0 * 16);
    gl_lds16(vp1 + vo, dV + cid1 * 16);
  };

  f4 oacc[4][4] = {};
  f4 lacc[4] = {};
  h8 ones;
#pragma unroll
  for (int j = 0; j < 8; ++j) ones[j] = (_Float16)1.0f;
  _Float16* pw = sP + wave * 64 * 40;

  stage(0, 0); stage(1, 1);
  asm volatile("s_waitcnt vmcnt(4)" ::: "memory");   // tile0 landed; tile1 in flight
  BAR();

  int cur = 0, nb = 2;
  for (int it = 0; it < 16; ++it) {
    if (it < 14) stage(it + 2, nb);               // 2-deep prefetch
    const char* sK = sKV + cur * 16384;
    const char* sV = sK + 8192;
    for (int mh = 0; mh < 2; ++mh) {
      // S^T = K . Q^T for this 32-key half
      f4 sacc[2][4] = {};
#pragma unroll
      for (int kk = 0; kk < 2; ++kk) {
        h8 kf[2];
        int ch = kk * 4 + l4;
#pragma unroll
        for (int mt = 0; mt < 2; ++mt) {
          int r = mh * 32 + mt * 16 + l15;
          kf[mt] = *(const h8*)(sK + ((r * 8 + (ch ^ (r & 7))) * 16));
        }
#pragma unroll
        for (int mt = 0; mt < 2; ++mt)
#pragma unroll
          for (int nt = 0; nt < 4; ++nt)
            sacc[mt][nt] = MFMA(kf[mt], qf[nt][kk], sacc[mt][nt]);
      }
      // exp2 (raw v_exp_f32; args bounded) + pkrtz pack, write P-half (stride 40 fp16)
#pragma unroll
      for (int mt = 0; mt < 2; ++mt) {
#pragma unroll
        for (int nt = 0; nt < 4; ++nt) {
          float p0 = __builtin_amdgcn_exp2f(sacc[mt][nt][0]);
          float p1 = __builtin_amdgcn_exp2f(sacc[mt][nt][1]);
          float p2 = __builtin_amdgcn_exp2f(sacc[mt][nt][2]);
          float p3 = __builtin_amdgcn_exp2f(sacc[mt][nt][3]);
          union { fp16x2 h[2]; h4 v; } uu;
          uu.h[0] = __builtin_amdgcn_cvt_pkrtz(p0, p1);
          uu.h[1] = __builtin_amdgcn_cvt_pkrtz(p2, p3);
          *(h4*)(pw + (nt * 16 + l15) * 40 + mt * 16 + l4 * 4) = uu.v;
        }
      }
      // PV for this half (k=32 = one MFMA K); row sums via ones-MFMA
      h8 pf[4], vf[4];
#pragma unroll
      for (int mi = 0; mi < 4; ++mi)
        pf[mi] = *(const h8*)(pw + (mi * 16 + l15) * 40 + l4 * 8);
      int ch = mh * 4 + l4;
#pragma unroll
      for (int nd = 0; nd < 4; ++nd) {
        int r = nd * 16 + l15;
        vf[nd] = *(const h8*)(sV + ((r * 8 + (ch ^ (r & 7))) * 16));
      }
#pragma unroll
      for (int mi = 0; mi < 4; ++mi) {
#pragma unroll
        for (int nd = 0; nd < 4; ++nd)
          oacc[mi][nd] = MFMA(pf[mi], vf[nd], oacc[mi][nd]);
        lacc[mi] = MFMA(pf[mi], ones, lacc[mi]);
      }
    }
    // counted drain: st(it+1) must land; st(it+2) stays in flight.
    if (it < 14) asm volatile("s_waitcnt vmcnt(4)" ::: "memory");
    else         asm volatile("s_waitcnt vmcnt(0)" ::: "memory");
    BAR();
    cur = (cur == 2) ? 0 : cur + 1;
    nb = (nb == 2) ? 0 : nb + 1;
  }
  // normalize + write (row sum already per-lane in lacc, C-layout aligned with oacc)
  int b = bh >> 4, h = bh & 15;
#pragma unroll
  for (int mi = 0; mi < 4; ++mi) {
#pragma unroll
    for (int r = 0; r < 4; ++r) {
      float inv = __builtin_amdgcn_rcpf(lacc[mi][r]);   // fp16 output: rcp error invisible
      int t = qt + wave * 64 + mi * 16 + l4 * 4 + r;
#pragma unroll
      for (int nd = 0; nd < 4; ++nd)
        O[(size_t)(b * 1024 + t) * 1024 + h * 64 + nd * 16 + l15] =
            (_Float16)(oacc[mi][nd][r] * inv);
    }
  }
}

// ---------------- GEMM2: out = attn(16384x1024) @ woutT(1024x1024)^T + b, fp32 out ----------------
__global__ __launch_bounds__(512) void k_gemm_out(
    const _Float16* __restrict__ A, const _Float16* __restrict__ BT,
    const float* __restrict__ bias, float* __restrict__ C) {
  __shared__ char smem[131072];
  int id = blockIdx.x;                        // 256 blocks, 256 % 8 == 0
  int swz = (id & 7) * 32 + (id >> 3);
  int by = swz >> 2, bx = swz & 3;
  int tm = by * 256, tn = bx * 256;
  f4 acc[8][4] = {};
  gemm256_tile(A + (size_t)tm * 1024, BT + (size_t)tn * 1024, nullptr,
               true, false, smem, acc);

  int tid = threadIdx.x, lane = tid & 63, wave = tid >> 6;
  int l15 = lane & 15, l4 = lane >> 4;
  int wm = (wave >> 2) * 128, wn = (wave & 3) * 64;
#pragma unroll
  for (int nj = 0; nj < 4; ++nj) {
    int n = tn + wn + nj * 16 + l15;
    float bv = bias[n];
#pragma unroll
    for (int mig = 0; mig < 8; ++mig) {
#pragma unroll
      for (int r = 0; r < 4; ++r) {
        int m = tm + wm + mig * 16 + l4 * 4 + r;
        C[(size_t)m * 1024 + n] = acc[mig][nj][r] + bv;
      }
    }
  }
}

extern "C" void kernel_launch(void* const* d_in, const int* in_sizes, int n_in,
                              void* d_out, int out_size, void* d_ws, size_t ws_size,
                              hipStream_t stream) {
  const float* hs    = (const float*)d_in[0];
  const float* w_qkv = (const float*)d_in[1];
  const float* b_qkv = (const float*)d_in[2];
  const float* w_out = (const float*)d_in[3];
  const float* b_out = (const float*)d_in[4];
  float* out = (float*)d_out;
  char* ws = (char*)d_ws;

  _Float16* hs_h  = (_Float16*)(ws);                          // 33,554,432 B (reused as attn out)
  _Float16* wqkvT = (_Float16*)(ws + 33554432);               //  6,291,456 B
  _Float16* woutT = (_Float16*)(ws + 39845888);               //  2,097,152 B
  _Float16* q_ws  = (_Float16*)(ws + 41943040);               // 33,554,432 B
  _Float16* k_ws  = (_Float16*)(ws + 75497472);               // 33,554,432 B
  _Float16* vt_ws = (_Float16*)(ws + 109051904);              // 33,554,432 B (V, transposed)

  k_pre<<<9216, 256, 0, stream>>>(hs, hs_h, w_qkv, wqkvT, w_out, woutT);
  k_gemm_qkv<<<256, 512, 0, stream>>>(hs_h, wqkvT, b_qkv, q_ws, k_ws, vt_ws);
  _Float16* attn_h = hs_h;  // hs_h no longer needed after gemm_qkv
  k_attn<<<dim3(4, 256), 256, 0, stream>>>(q_ws, k_ws, vt_ws, attn_h);
  k_gemm_out<<<256, 512, 0, stream>>>(attn_h, woutT, b_out, out);
}